// Round 2
// baseline (766.191 us; speedup 1.0000x reference)
//
#include <hip/hip_runtime.h>
#include <hip/hip_bf16.h>

#define BATCH 16
#define NN 1024
#define MM 1024
#define DD 512

#define LOG2E 1.4426950408889634f
#define LN2f  0.6931471805599453f
#define NEGS  -1.442695e9f   // NEG (-1e9) scaled by log2e; acts as -inf sentinel

// nw_dp geometry (PROVEN round-0 shape): 4 waves per batch, 4 rows/lane,
// stagger 128 cols, barrier every 64. Two batches share one 512-thread block
// so each SIMD carries 2 INDEPENDENT waves (different batches).
#define DSTAG 128
#define PF    8               // theta prefetch depth (iterations)
#define GTOT  1472            // 1023 + 3*128 + 63 + 1 = 1472, multiple of 8

typedef __bf16 v8bf __attribute__((ext_vector_type(8)));
typedef __bf16 v4bf __attribute__((ext_vector_type(4)));
typedef float  v4f  __attribute__((ext_vector_type(4)));

// ---------------------------------------------------------------- zero A acc
__global__ void zero_acc(float* a) {
    if (threadIdx.x < BATCH) a[threadIdx.x] = 0.0f;
}

// ------------------------------------------- fp32->bf16 convert + gap-dot
__global__ __launch_bounds__(256) void conv_reduce(
        const float* __restrict__ zx, const float* __restrict__ zy,
        const float* __restrict__ gw,
        __bf16* __restrict__ zxb, __bf16* __restrict__ zyb,
        float* __restrict__ acc) {
    const int chunk = blockIdx.x, b = blockIdx.y, which = blockIdx.z;
    const float* src = which ? zy : zx;
    __bf16* dst = which ? zyb : zxb;
    const float* g = gw + which * DD;
    const size_t base = ((size_t)b * NN + (size_t)chunk * 64) * DD;
    const int t = threadIdx.x;
    const int col = (t * 4) & (DD - 1);
    const float4 gv = *(const float4*)(g + col);
    float sum = 0.0f;
    #pragma unroll 4
    for (int it = 0; it < 32; ++it) {
        size_t off = base + (size_t)it * 1024 + t * 4;
        float4 x = *(const float4*)(src + off);
        sum += x.x * gv.x + x.y * gv.y + x.z * gv.z + x.w * gv.w;
        v4bf o = { (__bf16)x.x, (__bf16)x.y, (__bf16)x.z, (__bf16)x.w };
        *(v4bf*)(dst + off) = o;
    }
    #pragma unroll
    for (int o = 32; o > 0; o >>= 1) sum += __shfl_down(sum, o);
    __shared__ float wsum[4];
    if ((t & 63) == 0) wsum[t >> 6] = sum;
    __syncthreads();
    if (t == 0) {
        float s = wsum[0] + wsum[1] + wsum[2] + wsum[3];
        atomicAdd(acc + b, s * (1.0f / 1024.0f));
    }
}

// ------------------------------------------------------- bf16 MFMA NT GEMM
// out[row i][col j] = sum_d A[i,d]*B[j,d].  Called with A=zyb, B=zxb so the
// output buffer is thetaT[j_theta][i_theta] (theta transposed) at zero cost.
__global__ __launch_bounds__(256) void gemm_bt(
        const __bf16* __restrict__ Abf, const __bf16* __restrict__ Bbf,
        float* __restrict__ theta) {
    __shared__ __bf16 As[64 * 40];
    __shared__ __bf16 Bs[64 * 40];
    const int b = blockIdx.z;
    const int i0 = blockIdx.y * 64, j0 = blockIdx.x * 64;
    const __bf16* ap = Abf + ((size_t)b * NN + i0) * DD;
    const __bf16* bp = Bbf + ((size_t)b * MM + j0) * DD;
    const int t = threadIdx.x;
    const int srow = t >> 2, scol = (t & 3) * 8;
    const int lane = t & 63, wave = t >> 6;
    const int mrow = lane & 15, quad = lane >> 4;
    v4f acc[4] = {};
    for (int kk = 0; kk < DD; kk += 32) {
        if (kk) __syncthreads();
        *(v8bf*)&As[srow * 40 + scol] = *(const v8bf*)(ap + (size_t)srow * DD + kk + scol);
        *(v8bf*)&Bs[srow * 40 + scol] = *(const v8bf*)(bp + (size_t)srow * DD + kk + scol);
        __syncthreads();
        v8bf af = *(const v8bf*)&As[(wave * 16 + mrow) * 40 + quad * 8];
        #pragma unroll
        for (int tt = 0; tt < 4; ++tt) {
            v8bf bf = *(const v8bf*)&Bs[(tt * 16 + mrow) * 40 + quad * 8];
            acc[tt] = __builtin_amdgcn_mfma_f32_16x16x32_bf16(af, bf, acc[tt], 0, 0, 0);
        }
    }
    const size_t tb = (size_t)b * NN * MM;
    #pragma unroll
    for (int tt = 0; tt < 4; ++tt) {
        int j = j0 + tt * 16 + mrow;
        #pragma unroll
        for (int r = 0; r < 4; ++r) {
            int i = i0 + wave * 16 + quad * 4 + r;
            theta[tb + (size_t)i * MM + j] = acc[tt][r];
        }
    }
}

// --------------------------------------------------- soft-NW wavefront DP
// Two batches per 512-thread block: waves 0-3 -> batch 2*blk, waves 4-7 ->
// batch 2*blk+1. Per batch this is EXACTLY the proven round-0 geometry
// (4 waves, 4 rows/lane, DSTAG=128, LDS ring, barrier every 64 iters); the
// pairing puts 2 INDEPENDENT waves on each SIMD so one batch's issue stream
// fills the other's dependence stalls (they share only the rare barrier).
// Serial-chain cuts vs round 0:
//  - single-shuffle: diag input tp at iter g == post-fixup tc of iter g-1
//    (incl. lane-0 ring case) -> one ds_bpermute + one ring read removed.
//  - "1+" lse3: max term is exp2(0)=1 -> ss = 1+exp2(med-mx)+exp2(mn-mx)
//    via v_max3/v_med3/v_min3 (one fewer transcendental per cell).
//  - c1 folding: c1 = fma(th,log2e,mx) and c1+Ac are computed off the carried
//    chain; the chain is max3->sub->exp2->add->log2->add (~38 cyc/row).
__global__ __launch_bounds__(512) void nw_dp(
        const float* __restrict__ thetaT, const float* __restrict__ acc,
        const float* __restrict__ gap_b, float* __restrict__ out) {
    const int tid = threadIdx.x;
    const int half = tid >> 8;                 // which batch of the pair
    const int b = blockIdx.x * 2 + half;
    const int t = tid & 63, w = (tid >> 6) & 3;
    const float Ac = (acc[b] + gap_b[0]) * LOG2E;
    const int row0 = w * 256 + t * 4;          // theta rows row0..row0+3
    const int off = w * DSTAG + t;             // lane's column lag
    const float* Tb = thetaT + (size_t)b * NN * MM + row0;

    __shared__ float ring[2][3][256];

    float v[4];
    v[0] = v[1] = v[2] = v[3] = NEGS;
    float v3c = NEGS;                          // bottom-row value, prev iter
    float tcp = NEGS;                          // prev iteration's tc (post-fixup)

    float4 pf[PF];
    #pragma unroll
    for (int u = 0; u < PF; ++u) {
        int c0 = u - off;
        c0 = c0 < 0 ? 0 : c0;                  // u-off <= 7 < MM: low clamp only
        pf[u] = *(const float4*)(Tb + (size_t)c0 * NN);
    }
    float rtc = NEGS;                          // prefetched ring value (lane 0, w>0)

    for (int gg = 0; gg < GTOT; gg += PF) {
        #pragma unroll
        for (int u = 0; u < PF; ++u) {
            const int g = gg + u;
            const int c = g - off;

            float tc = __shfl_up(v3c, 1);      // up input: neighbor bottom @ col c
            if (t == 0) tc = (w == 0) ? NEGS : rtc;
            float tp = tcp;                    // diag input: prev iteration's tc
            if (t == 0 && c == 0) tp = (w == 0) ? 0.0f : NEGS;
            tcp = tc;

            const float4 cur = pf[u];
            // re-issue this slot: column g + PF - off
            int cn = g + PF - off;
            cn = cn < 0 ? 0 : (cn > MM - 1 ? MM - 1 : cn);
            pf[u] = *(const float4*)(Tb + (size_t)cn * NN);

            if ((unsigned)c < MM) {
                const float* th = (const float*)&cur;
                // left+gap terms use pre-update v[]: off the carried chain
                float lfA0 = v[0] + Ac, lfA1 = v[1] + Ac;
                float lfA2 = v[2] + Ac, lfA3 = v[3] + Ac;
                float uu = tc + Ac;            // carried value arrives as nv+Ac
                float dg = tp;
                #pragma unroll
                for (int k = 0; k < 4; ++k) {
                    float lf = k == 0 ? lfA0 : (k == 1 ? lfA1 : (k == 2 ? lfA2 : lfA3));
                    float mx = fmaxf(fmaxf(uu, dg), lf);
                    float md = __builtin_amdgcn_fmed3f(uu, dg, lf);
                    float mn = fminf(fminf(uu, dg), lf);
                    float ss = 1.0f + __builtin_amdgcn_exp2f(md - mx)
                                    + __builtin_amdgcn_exp2f(mn - mx);
                    float l  = __builtin_amdgcn_logf(ss);
                    float c1 = fmaf(th[k], LOG2E, mx);   // off-chain after mx
                    float nd = v[k];           // next row's diag (pre-update)
                    v[k] = l + c1;
                    uu   = l + (c1 + Ac);      // == v[k] + Ac, single chain add
                    dg = nd;
                }
                v3c = v[3];
                if (t == 63 && w < 3) ring[half][w][c & 255] = v[3];
            }

            if ((g & 63) == 63) __syncthreads();

            // ring prefetch for iteration g+1 (producer wrote column g+1-off
            // exactly 64 iterations earlier; exactly one barrier in between).
            if (t == 0 && w > 0) rtc = ring[half][w - 1][(g + 1 - off) & 255];
        }
    }
    if ((tid & 255) == 255) out[b] = v[3] * LN2f;
}

// ---------------------------------------------------------------- launcher
extern "C" void kernel_launch(void* const* d_in, const int* in_sizes, int n_in,
                              void* d_out, int out_size, void* d_ws, size_t ws_size,
                              hipStream_t stream) {
    const float* zx    = (const float*)d_in[0];
    const float* zy    = (const float*)d_in[1];
    const float* gw    = (const float*)d_in[2];
    const float* gapb  = (const float*)d_in[3];
    float* out = (float*)d_out;

    char* ws = (char*)d_ws;
    float*  thetaT = (float*)ws;                                  // 67,108,864 B
    __bf16* zxb   = (__bf16*)(ws + (size_t)67108864);             // 16,777,216 B
    __bf16* zyb   = (__bf16*)(ws + (size_t)67108864 + 16777216);  // 16,777,216 B
    float*  acc   = (float*)(ws + (size_t)67108864 + 2 * 16777216);

    zero_acc<<<1, 64, 0, stream>>>(acc);
    conv_reduce<<<dim3(16, BATCH, 2), 256, 0, stream>>>(zx, zy, gw, zxb, zyb, acc);
    // swapped args: output = theta^T
    gemm_bt<<<dim3(MM / 64, NN / 64, BATCH), 256, 0, stream>>>(zyb, zxb, thetaT);
    nw_dp<<<BATCH / 2, 512, 0, stream>>>(thetaT, acc, gapb, out);
}

// Round 3
// 540.132 us; speedup vs baseline: 1.4185x; 1.4185x over previous
//
#include <hip/hip_runtime.h>
#include <hip/hip_bf16.h>

#define BATCH 16
#define NN 1024
#define MM 1024
#define DD 512

#define LOG2E 1.4426950408889634f
#define LN2f  0.6931471805599453f
#define NEGS  -1.442695e9f   // NEG (-1e9) scaled by log2e; acts as -inf sentinel

// nw_dp geometry: PROVEN round-0 shell (16 blocks x 256 thr, 4 waves, barrier
// every 64 iters, LDS ring) but each iteration now processes a 4-row x 2-col
// tile per lane. Intra-tile critical path = 5 cells per 2 columns (vs 8),
// one shuffle pair per 2 columns, all fixed overhead amortized 2x.
// Lane stagger = 2 cols, so DSTAG must satisfy: producer-consumer iteration
// gap = (DSTAG-126)/2 - 1 = 64 >= barrier period (one barrier always between
// ring write and read), and ring WAR margin = 256 - 65 = 191 iters >> 64.
#define DSTAG 256
#define PF    8               // theta prefetch depth (iterations)
#define GTOT  960             // max g = (1022 + 3*256 + 126)/2 = 958; mult of 8

typedef __bf16 v8bf __attribute__((ext_vector_type(8)));
typedef __bf16 v4bf __attribute__((ext_vector_type(4)));
typedef float  v4f  __attribute__((ext_vector_type(4)));

// ---------------------------------------------------------------- zero A acc
__global__ void zero_acc(float* a) {
    if (threadIdx.x < BATCH) a[threadIdx.x] = 0.0f;
}

// ------------------------------------------- fp32->bf16 convert + gap-dot
__global__ __launch_bounds__(256) void conv_reduce(
        const float* __restrict__ zx, const float* __restrict__ zy,
        const float* __restrict__ gw,
        __bf16* __restrict__ zxb, __bf16* __restrict__ zyb,
        float* __restrict__ acc) {
    const int chunk = blockIdx.x, b = blockIdx.y, which = blockIdx.z;
    const float* src = which ? zy : zx;
    __bf16* dst = which ? zyb : zxb;
    const float* g = gw + which * DD;
    const size_t base = ((size_t)b * NN + (size_t)chunk * 64) * DD;
    const int t = threadIdx.x;
    const int col = (t * 4) & (DD - 1);
    const float4 gv = *(const float4*)(g + col);
    float sum = 0.0f;
    #pragma unroll 4
    for (int it = 0; it < 32; ++it) {
        size_t off = base + (size_t)it * 1024 + t * 4;
        float4 x = *(const float4*)(src + off);
        sum += x.x * gv.x + x.y * gv.y + x.z * gv.z + x.w * gv.w;
        v4bf o = { (__bf16)x.x, (__bf16)x.y, (__bf16)x.z, (__bf16)x.w };
        *(v4bf*)(dst + off) = o;
    }
    #pragma unroll
    for (int o = 32; o > 0; o >>= 1) sum += __shfl_down(sum, o);
    __shared__ float wsum[4];
    if ((t & 63) == 0) wsum[t >> 6] = sum;
    __syncthreads();
    if (t == 0) {
        float s = wsum[0] + wsum[1] + wsum[2] + wsum[3];
        atomicAdd(acc + b, s * (1.0f / 1024.0f));
    }
}

// ------------------------------------------------------- bf16 MFMA NT GEMM
// out[row i][col j] = sum_d A[i,d]*B[j,d].  Called with A=zyb, B=zxb so the
// output buffer is thetaT[j_theta][i_theta] (theta transposed) at zero cost.
__global__ __launch_bounds__(256) void gemm_bt(
        const __bf16* __restrict__ Abf, const __bf16* __restrict__ Bbf,
        float* __restrict__ theta) {
    __shared__ __bf16 As[64 * 40];
    __shared__ __bf16 Bs[64 * 40];
    const int b = blockIdx.z;
    const int i0 = blockIdx.y * 64, j0 = blockIdx.x * 64;
    const __bf16* ap = Abf + ((size_t)b * NN + i0) * DD;
    const __bf16* bp = Bbf + ((size_t)b * MM + j0) * DD;
    const int t = threadIdx.x;
    const int srow = t >> 2, scol = (t & 3) * 8;
    const int lane = t & 63, wave = t >> 6;
    const int mrow = lane & 15, quad = lane >> 4;
    v4f acc[4] = {};
    for (int kk = 0; kk < DD; kk += 32) {
        if (kk) __syncthreads();
        *(v8bf*)&As[srow * 40 + scol] = *(const v8bf*)(ap + (size_t)srow * DD + kk + scol);
        *(v8bf*)&Bs[srow * 40 + scol] = *(const v8bf*)(bp + (size_t)srow * DD + kk + scol);
        __syncthreads();
        v8bf af = *(const v8bf*)&As[(wave * 16 + mrow) * 40 + quad * 8];
        #pragma unroll
        for (int tt = 0; tt < 4; ++tt) {
            v8bf bf = *(const v8bf*)&Bs[(tt * 16 + mrow) * 40 + quad * 8];
            acc[tt] = __builtin_amdgcn_mfma_f32_16x16x32_bf16(af, bf, acc[tt], 0, 0, 0);
        }
    }
    const size_t tb = (size_t)b * NN * MM;
    #pragma unroll
    for (int tt = 0; tt < 4; ++tt) {
        int j = j0 + tt * 16 + mrow;
        #pragma unroll
        for (int r = 0; r < 4; ++r) {
            int i = i0 + wave * 16 + quad * 4 + r;
            theta[tb + (size_t)i * MM + j] = acc[tt][r];
        }
    }
}

// --------------------------------------------------- soft-NW wavefront DP
// 4 waves per batch (256 threads). Wave w owns V-rows 256w+1..256w+256, lane
// owns 4 rows, and processes a 4x2 tile (cols C, C+1) per iteration.
// Intra-tile dependency wavefront: critical path 5 cells per 2 columns.
// Inputs per iter: ta=V[row0-1][C], tb=V[row0-1][C+1] (shuffle pair / ring),
// tp=V[row0-1][C-1] (== prev iter's post-fixup tb, single-shuffle trick).
// Chain cuts (proven correct in rounds 1-2, absmax 0):
//  - "1+" lse3: ss = 1 + exp2(med-mx) + exp2(mn-mx) via max3/med3/min3
//  - c1 folding: c1 = fma(th,log2e,mx) off-chain; uu = l + (c1+Ac)
__global__ __launch_bounds__(256) void nw_dp(
        const float* __restrict__ thetaT, const float* __restrict__ acc,
        const float* __restrict__ gap_b, float* __restrict__ out) {
    const int b = blockIdx.x;
    const int tid = threadIdx.x;
    const int t = tid & 63, w = tid >> 6;
    const float Ac = (acc[b] + gap_b[0]) * LOG2E;
    const int row0 = w * 256 + t * 4;          // theta rows row0..row0+3
    const int off2 = w * DSTAG + 2 * t;        // lane's column lag (cols)
    const float* Tb = thetaT + (size_t)b * NN * MM + row0;

    __shared__ float2 ring[3][256];            // 256 slots x 2 cols = 512-col span

    float v0 = NEGS, v1 = NEGS, v2 = NEGS, v3 = NEGS;
    float v3a = NEGS, v3b = NEGS;              // bottom-row values @ my cols C,C+1
    float tpp = NEGS;                          // prev iteration's tb (post-fixup)
    float2 rt; rt.x = NEGS; rt.y = NEGS;       // ring prefetch (lane 0, w>0)

    float4 pfA[PF], pfB[PF];
    #pragma unroll
    for (int u = 0; u < PF; ++u) {
        int c0 = 2 * u - off2;                 // <= 14, low clamp only
        int ca = c0 < 0 ? 0 : c0;
        int cb = c0 + 1 < 0 ? 0 : c0 + 1;
        pfA[u] = *(const float4*)(Tb + (size_t)ca * NN);
        pfB[u] = *(const float4*)(Tb + (size_t)cb * NN);
    }

    // one cell: updates vk (row value), uu (next row's up+Ac), dg (next diag)
    #define CELL(vk, th) {                                                   \
        float lf = vk + Ac;                                                  \
        float mx = fmaxf(fmaxf(uu, dg), lf);                                 \
        float md = __builtin_amdgcn_fmed3f(uu, dg, lf);                      \
        float mn = fminf(fminf(uu, dg), lf);                                 \
        float ss = 1.0f + __builtin_amdgcn_exp2f(md - mx)                    \
                        + __builtin_amdgcn_exp2f(mn - mx);                   \
        float l  = __builtin_amdgcn_logf(ss);                                \
        float c1 = fmaf(th, LOG2E, mx);                                      \
        dg = vk;                                                             \
        vk = l + c1;                                                         \
        uu = l + (c1 + Ac);                                                  \
    }

    for (int gg = 0; gg < GTOT; gg += PF) {
        #pragma unroll
        for (int u = 0; u < PF; ++u) {
            const int g = gg + u;
            const int C = 2 * g - off2;        // even; C valid => C+1 valid

            float ta = __shfl_up(v3a, 1);      // V[row0-1][C]
            float tb = __shfl_up(v3b, 1);      // V[row0-1][C+1]
            if (t == 0) {
                if (w == 0) { ta = NEGS; tb = NEGS; }
                else        { ta = rt.x; tb = rt.y; }
            }
            float tp = tpp;                    // V[row0-1][C-1]
            if (t == 0 && C == 0) tp = (w == 0) ? 0.0f : NEGS;
            tpp = tb;

            const float4 curA = pfA[u], curB = pfB[u];
            // re-issue this slot: columns for iteration g + PF
            int cn = 2 * (g + PF) - off2;
            int ca = cn < 0 ? 0 : (cn > MM - 1 ? MM - 1 : cn);
            int cb = cn + 1 < 0 ? 0 : (cn + 1 > MM - 1 ? MM - 1 : cn + 1);
            pfA[u] = *(const float4*)(Tb + (size_t)ca * NN);
            pfB[u] = *(const float4*)(Tb + (size_t)cb * NN);

            if ((unsigned)C < MM) {
                float uu, dg;
                // column C
                uu = ta + Ac; dg = tp;
                CELL(v0, curA.x) CELL(v1, curA.y) CELL(v2, curA.z) CELL(v3, curA.w)
                v3a = v3;
                // column C+1 (diag of top cell = V[row0-1][C] = ta)
                uu = tb + Ac; dg = ta;
                CELL(v0, curB.x) CELL(v1, curB.y) CELL(v2, curB.z) CELL(v3, curB.w)
                v3b = v3;
                if (t == 63 && w < 3) {
                    float2 pr; pr.x = v3a; pr.y = v3b;
                    ring[w][(C >> 1) & 255] = pr;
                }
            }

            if ((g & 63) == 63) __syncthreads();

            // ring prefetch for iteration g+1 (producer wrote these columns
            // 65 iterations earlier; >=1 barrier strictly between; WAR
            // margin 191 iterations with 256 slots).
            if (t == 0 && w > 0) {
                int c0n = 2 * (g + 1) - w * DSTAG;   // lane 0's next col C
                rt = ring[w - 1][(c0n >> 1) & 255];
            }
        }
    }
    #undef CELL
    if (tid == 255) out[b] = v3 * LN2f;
}

// ---------------------------------------------------------------- launcher
extern "C" void kernel_launch(void* const* d_in, const int* in_sizes, int n_in,
                              void* d_out, int out_size, void* d_ws, size_t ws_size,
                              hipStream_t stream) {
    const float* zx    = (const float*)d_in[0];
    const float* zy    = (const float*)d_in[1];
    const float* gw    = (const float*)d_in[2];
    const float* gapb  = (const float*)d_in[3];
    float* out = (float*)d_out;

    char* ws = (char*)d_ws;
    float*  thetaT = (float*)ws;                                  // 67,108,864 B
    __bf16* zxb   = (__bf16*)(ws + (size_t)67108864);             // 16,777,216 B
    __bf16* zyb   = (__bf16*)(ws + (size_t)67108864 + 16777216);  // 16,777,216 B
    float*  acc   = (float*)(ws + (size_t)67108864 + 2 * 16777216);

    zero_acc<<<1, 64, 0, stream>>>(acc);
    conv_reduce<<<dim3(16, BATCH, 2), 256, 0, stream>>>(zx, zy, gw, zxb, zyb, acc);
    // swapped args: output = theta^T
    gemm_bt<<<dim3(MM / 64, NN / 64, BATCH), 256, 0, stream>>>(zyb, zxb, thetaT);
    nw_dp<<<BATCH, 256, 0, stream>>>(thetaT, acc, gapb, out);
}